// Round 15
// baseline (84.690 us; speedup 1.0000x reference)
//
#include <hip/hip_runtime.h>

#define B_   32
#define H_   16
#define L_   577
#define D_   1024
#define CK   64
#define LP   576    // L-1 patches = 9*64 = 8*72 exactly
#define DOM  54
#define NSEL 55     // DOM + CLS
#define NR   522    // LP - DOM
#define CTX  10
#define NMERGE 512  // NR - CTX

// remain-list position for merge index m: p = m + min(m/51,9) + 1
__device__ __forceinline__ int remain_pos(int m) {
    int k = m / 51; if (k > 9) k = 9;
    return m + k + 1;
}

// position of r-th (0-indexed) set bit of x (must exist)
__device__ __forceinline__ int nth_set_bit64(unsigned long long x, int r) {
    int pos = 0;
    #pragma unroll
    for (int sh = 32; sh >= 1; sh >>= 1) {
        int c = __popcll(x & ((1ull << sh) - 1));
        if (r >= c) { r -= c; x >>= sh; pos += sh; }
    }
    return pos;
}
// r-th zero position over 576-bit mask (9 u64 words)
__device__ int nth_zero_576(const unsigned long long* w, int r) {
    #pragma unroll
    for (int i = 0; i < 9; ++i) {
        int c = 64 - __popcll(w[i]);
        if (r < c) return i * 64 + nth_set_bit64(~w[i], r);
        r -= c;
    }
    return 0; // unreachable
}
// r-th set position over 576-bit mask
__device__ int nth_set_576(const unsigned long long* w, int r) {
    #pragma unroll
    for (int i = 0; i < 9; ++i) {
        int c = __popcll(w[i]);
        if (r < c) return i * 64 + nth_set_bit64(w[i], r);
        r -= c;
    }
    return 0; // unreachable
}

// K1 (FUSED pre+rank): block = (batch, 64-j slice), 512 threads.
// Each block recomputes its batch's full Sd+cos (L2/L3-hot, 9x redundant),
// z-scores, ranks its 64 js, emits one selbits word.
__global__ __launch_bounds__(512) void k_score(
    const float* __restrict__ attn, const float* __restrict__ metric,
    const float* __restrict__ text, unsigned long long* __restrict__ selbits)
{
    const int b = blockIdx.x / 9, slice = blockIdx.x % 9;
    const int tid = threadIdx.x, wv = tid >> 6, lane = tid & 63;

    __shared__ float sdv[LP];
    __shared__ float csv[LP];
    __shared__ float tsh[CK];
    __shared__ float red[16];
    __shared__ int   prank[512];
    __shared__ float sh_invtn;

    // text stage + inv norm
    if (tid < CK) {
        float t = text[b * CK + tid];
        tsh[tid] = t;
        float s2 = t * t;
        for (int o = 32; o; o >>= 1) s2 += __shfl_xor(s2, o);
        if (tid == 0) sh_invtn = 1.f / (sqrtf(s2) + 1e-12f);
    }

    // Sd: coalesced per head (j = tid, tid+512)
    {
        const size_t LL = (size_t)L_ * L_;
        for (int j = tid; j < LP; j += 512) {
            size_t base = (size_t)b * H_ * LL + 1 + j;
            float s = 0.f;
            #pragma unroll
            for (int h = 0; h < H_; ++h) s += attn[base + h * LL];
            sdv[j] = s;
        }
    }
    __syncthreads();
    const float inv_tn = sh_invtn;

    // cos: wave-per-token, 72 iters/wave, independent pipelined loads
    for (int t = wv; t < LP; t += 8) {
        float m = metric[((size_t)(b * L_ + 1 + t)) * CK + lane];
        float d = m * tsh[lane], ss = m * m;
        for (int o = 32; o; o >>= 1) { d += __shfl_xor(d, o); ss += __shfl_xor(ss, o); }
        if (lane == 0) csv[t] = d / (sqrtf(ss) + 1e-12f) * inv_tn;
    }
    __syncthreads();

    // stats (identical across a batch's 9 blocks: same code, same data)
    float sumS = 0.f, sumC = 0.f;
    for (int j = tid; j < LP; j += 512) { sumS += sdv[j]; sumC += csv[j]; }
    for (int o = 32; o; o >>= 1) { sumS += __shfl_xor(sumS, o); sumC += __shfl_xor(sumC, o); }
    if (lane == 0) { red[wv] = sumS; red[8 + wv] = sumC; }
    __syncthreads();
    const float mS = (((red[0]+red[1])+(red[2]+red[3])) + ((red[4]+red[5])+(red[6]+red[7]))) * (1.f / LP);
    const float mC = (((red[8]+red[9])+(red[10]+red[11])) + ((red[12]+red[13])+(red[14]+red[15]))) * (1.f / LP);
    __syncthreads();   // before red reuse

    float s2S = 0.f, s2C = 0.f;
    for (int j = tid; j < LP; j += 512) {
        float dS = sdv[j] - mS, dC = csv[j] - mC;
        s2S += dS * dS; s2C += dC * dC;
    }
    for (int o = 32; o; o >>= 1) { s2S += __shfl_xor(s2S, o); s2C += __shfl_xor(s2C, o); }
    if (lane == 0) { red[wv] = s2S; red[8 + wv] = s2C; }
    __syncthreads();
    const float vS = (((red[0]+red[1])+(red[2]+red[3])) + ((red[4]+red[5])+(red[6]+red[7]))) * (1.f / (LP - 1));
    const float vC = (((red[8]+red[9])+(red[10]+red[11])) + ((red[12]+red[13])+(red[14]+red[15]))) * (1.f / (LP - 1));
    const float izS = 0.5f / (sqrtf(vS) + 1e-6f);
    const float izC = 0.5f / (sqrtf(vC) + 1e-6f);
    __syncthreads();

    for (int j = tid; j < LP; j += 512)
        sdv[j] = (sdv[j] - mS) * izS + (csv[j] - mC) * izC;
    __syncthreads();

    // rank slice: wave wv scans ks [72wv, 72wv+72) for js slice*64+lane
    {
        const int j = slice * 64 + lane;
        const float my = sdv[j];
        int rk = 0;
        const int k0 = 72 * wv;
        for (int k = k0; k < k0 + 72; ++k) {
            float s = sdv[k];
            rk += (s > my) || (s == my && k < j);   // stable: score desc, idx asc
        }
        prank[tid] = rk;
    }
    __syncthreads();
    if (tid < 64) {
        int tot = 0;
        #pragma unroll
        for (int q = 0; q < 8; ++q) tot += prank[tid + 64 * q];
        unsigned long long bm = __ballot(tot < DOM);
        if (tid == 0) selbits[b * 9 + slice] = bm;
    }
}

// K2: 8 threads/token argmax assignment — proven R14
__global__ __launch_bounds__(512) void k_assign(
    const float* __restrict__ metric,
    const unsigned long long* __restrict__ selbits,
    int* __restrict__ assign_tok)
{
    const int b = blockIdx.x >> 3, sub = blockIdx.x & 7;
    const int tid = threadIdx.x;
    const int wv = tid >> 6, lane = tid & 63;
    __shared__ int   t10[CTX];
    __shared__ float tg[CTX * CK];
    __shared__ float tinv[CTX];

    unsigned long long w[9];
    #pragma unroll
    for (int i = 0; i < 9; ++i) w[i] = selbits[b * 9 + i];

    if (tid < CTX) t10[tid] = nth_zero_576(w, 52 * tid) + 1;
    __syncthreads();
    if (tid < CTX * CK)
        tg[tid] = metric[((size_t)(b * L_ + t10[tid >> 6])) * CK + (tid & 63)];
    {
        int i2 = tid + 512;
        if (i2 < CTX * CK)
            tg[i2] = metric[((size_t)(b * L_ + t10[i2 >> 6])) * CK + (i2 & 63)];
    }
    __syncthreads();
    if (wv < 5) {
        #pragma unroll
        for (int q = 0; q < 2; ++q) {
            int k = 2 * wv + q;
            float t = tg[k * CK + lane];
            float s2 = t * t;
            for (int o = 32; o; o >>= 1) s2 += __shfl_xor(s2, o);
            if (lane == 0) tinv[k] = 1.f / (sqrtf(s2) + 1e-12f);
        }
    }
    __syncthreads();

    const int m = sub * 64 + (tid >> 3);      // token index
    const int e = tid & 7;                     // component-eighth
    const int tok = nth_zero_576(w, remain_pos(m)) + 1;
    const float4* row = (const float4*)&metric[((size_t)(b * L_ + tok)) * CK + 8 * e];
    float4 r0 = row[0], r1 = row[1];

    // merge-row norm dropped: positive scalar, argmax-invariant
    float best = -1e30f; int bk = 0;
    #pragma unroll
    for (int k = 0; k < CTX; ++k) {
        const float4* tp = (const float4*)&tg[k * CK + 8 * e];
        float4 t0 = tp[0], t1 = tp[1];
        float d = (r0.x*t0.x + r0.y*t0.y + r0.z*t0.z + r0.w*t0.w) +
                  (r1.x*t1.x + r1.y*t1.y + r1.z*t1.z + r1.w*t1.w);
        d += __shfl_xor(d, 1); d += __shfl_xor(d, 2); d += __shfl_xor(d, 4);
        d *= tinv[k];
        if (d > best) { best = d; bk = k; }   // strict >: first max (jnp.argmax)
    }
    if (e == 0) assign_tok[b * NMERGE + m] = (tok << 4) | bk;
}

// K3: heavy blocks first + dominant copies — proven R12/R14
__global__ __launch_bounds__(256) void k_out(
    const float* __restrict__ hidden,
    const unsigned long long* __restrict__ selbits,
    const int* __restrict__ assign_tok, float* __restrict__ out)
{
    const int blk = blockIdx.x;
    const int tid = threadIdx.x;

    if (blk < B_ * CTX) {
        const int b = blk / CTX, k = blk % CTX;
        const int w = tid >> 6, lane = tid & 63;
        __shared__ int at[NMERGE];
        __shared__ int toks[NMERGE];
        __shared__ unsigned long long cmask[2][4];

        at[tid]       = assign_tok[b * NMERGE + tid];
        at[tid + 256] = assign_tok[b * NMERGE + tid + 256];
        __syncthreads();
        int a0 = at[tid], a1 = at[tid + 256];
        bool m0 = (a0 & 15) == k, m1 = (a1 & 15) == k;
        unsigned long long bl0 = __ballot(m0), bl1 = __ballot(m1);
        if (lane == 0) { cmask[0][w] = bl0; cmask[1][w] = bl1; }
        __syncthreads();
        int sum0 = 0, pre0 = 0, pre1 = 0;
        #pragma unroll
        for (int ww = 0; ww < 4; ++ww) {
            int p0 = __popcll(cmask[0][ww]);
            sum0 += p0;
            if (ww < w) { pre0 += p0; pre1 += __popcll(cmask[1][ww]); }
        }
        int sum1 = 0;
        #pragma unroll
        for (int ww = 0; ww < 4; ++ww) sum1 += __popcll(cmask[1][ww]);
        unsigned long long lt = (1ull << lane) - 1ull;
        if (m0) toks[pre0 + __popcll(bl0 & lt)] = a0 >> 4;
        if (m1) toks[sum0 + pre1 + __popcll(bl1 & lt)] = a1 >> 4;
        const int cnt = sum0 + sum1;
        __syncthreads();

        const float4* hb = (const float4*)&hidden[((size_t)b * L_) * D_];
        float4 a_0 = make_float4(0,0,0,0), a_1 = a_0, a_2 = a_0, a_3 = a_0;
        float4 a_4 = a_0, a_5 = a_0, a_6 = a_0, a_7 = a_0;
        int i = 0;
        for (; i + 8 <= cnt; i += 8) {
            float4 v0 = hb[(size_t)toks[i+0] * 256 + tid];
            float4 v1 = hb[(size_t)toks[i+1] * 256 + tid];
            float4 v2 = hb[(size_t)toks[i+2] * 256 + tid];
            float4 v3 = hb[(size_t)toks[i+3] * 256 + tid];
            float4 v4 = hb[(size_t)toks[i+4] * 256 + tid];
            float4 v5 = hb[(size_t)toks[i+5] * 256 + tid];
            float4 v6 = hb[(size_t)toks[i+6] * 256 + tid];
            float4 v7 = hb[(size_t)toks[i+7] * 256 + tid];
            a_0.x += v0.x; a_0.y += v0.y; a_0.z += v0.z; a_0.w += v0.w;
            a_1.x += v1.x; a_1.y += v1.y; a_1.z += v1.z; a_1.w += v1.w;
            a_2.x += v2.x; a_2.y += v2.y; a_2.z += v2.z; a_2.w += v2.w;
            a_3.x += v3.x; a_3.y += v3.y; a_3.z += v3.z; a_3.w += v3.w;
            a_4.x += v4.x; a_4.y += v4.y; a_4.z += v4.z; a_4.w += v4.w;
            a_5.x += v5.x; a_5.y += v5.y; a_5.z += v5.z; a_5.w += v5.w;
            a_6.x += v6.x; a_6.y += v6.y; a_6.z += v6.z; a_6.w += v6.w;
            a_7.x += v7.x; a_7.y += v7.y; a_7.z += v7.z; a_7.w += v7.w;
        }
        for (; i < cnt; ++i) {
            float4 v = hb[(size_t)toks[i] * 256 + tid];
            a_0.x += v.x; a_0.y += v.y; a_0.z += v.z; a_0.w += v.w;
        }
        float4 acc;
        acc.x = ((a_0.x + a_1.x) + (a_2.x + a_3.x)) + ((a_4.x + a_5.x) + (a_6.x + a_7.x));
        acc.y = ((a_0.y + a_1.y) + (a_2.y + a_3.y)) + ((a_4.y + a_5.y) + (a_6.y + a_7.y));
        acc.z = ((a_0.z + a_1.z) + (a_2.z + a_3.z)) + ((a_4.z + a_5.z) + (a_6.z + a_7.z));
        acc.w = ((a_0.w + a_1.w) + (a_2.w + a_3.w)) + ((a_4.w + a_5.w) + (a_6.w + a_7.w));

        unsigned long long wsel[9];
        #pragma unroll
        for (int ii = 0; ii < 9; ++ii) wsel[ii] = selbits[b * 9 + ii];
        const int tgt_tok = nth_zero_576(wsel, 52 * k) + 1;
        float4 bv = hb[(size_t)tgt_tok * 256 + tid];
        float inv = 1.0f / fmaxf((float)cnt, 1.0f);
        float4 o;
        o.x = bv.x + acc.x * inv; o.y = bv.y + acc.y * inv;
        o.z = bv.z + acc.z * inv; o.w = bv.w + acc.w * inv;
        ((float4*)&out[((size_t)(b * 65 + NSEL + k)) * D_])[tid] = o;
    } else {
        const int i2 = blk - B_ * CTX;
        const int b = i2 / NSEL, r = i2 % NSEL;
        int tok = 0;
        if (r > 0) {
            unsigned long long wsel[9];
            #pragma unroll
            for (int ii = 0; ii < 9; ++ii) wsel[ii] = selbits[b * 9 + ii];
            tok = nth_set_576(wsel, r - 1) + 1;
        }
        const float4* src = (const float4*)&hidden[((size_t)(b * L_ + tok)) * D_];
        ((float4*)&out[((size_t)(b * 65 + r)) * D_])[tid] = src[tid];
    }
}

extern "C" void kernel_launch(void* const* d_in, const int* in_sizes, int n_in,
                              void* d_out, int out_size, void* d_ws, size_t ws_size,
                              hipStream_t stream) {
    const float* attn   = (const float*)d_in[0];
    const float* hidden = (const float*)d_in[1];
    const float* metric = (const float*)d_in[2];
    const float* text   = (const float*)d_in[3];
    float* out = (float*)d_out;

    char* ws = (char*)d_ws;
    size_t off = 0;
    auto alloc = [&](size_t bytes) { void* p = ws + off; off = (off + bytes + 255) & ~(size_t)255; return p; };
    unsigned long long* selbits = (unsigned long long*)alloc((size_t)B_ * 9 * 8);
    int* assign_tok = (int*)alloc((size_t)B_ * NMERGE * 4);

    k_score <<<B_ * 9, 512, 0, stream>>>(attn, metric, text, selbits);
    k_assign<<<B_ * 8, 512, 0, stream>>>(metric, selbits, assign_tok);
    k_out   <<<B_ * 65, 256, 0, stream>>>(hidden, selbits, assign_tok, out);
}

// Round 16
// 40.463 us; speedup vs baseline: 2.0930x; 2.0930x over previous
//
#include <hip/hip_runtime.h>

#define B_   32
#define H_   16
#define L_   577
#define D_   1024
#define CK   64
#define LP   576    // L-1 patches = 9*64 exactly
#define DOM  54
#define NSEL 55     // DOM + CLS
#define NR   522    // LP - DOM
#define CTX  10
#define NMERGE 512  // NR - CTX
#define BL   (B_ * LP)

// remain-list position for merge index m: p = m + min(m/51,9) + 1
__device__ __forceinline__ int remain_pos(int m) {
    int k = m / 51; if (k > 9) k = 9;
    return m + k + 1;
}

// position of r-th (0-indexed) set bit of x (must exist)
__device__ __forceinline__ int nth_set_bit64(unsigned long long x, int r) {
    int pos = 0;
    #pragma unroll
    for (int sh = 32; sh >= 1; sh >>= 1) {
        int c = __popcll(x & ((1ull << sh) - 1));
        if (r >= c) { r -= c; x >>= sh; pos += sh; }
    }
    return pos;
}
// r-th zero position over 576-bit mask (9 u64 words)
__device__ int nth_zero_576(const unsigned long long* w, int r) {
    #pragma unroll
    for (int i = 0; i < 9; ++i) {
        int c = 64 - __popcll(w[i]);
        if (r < c) return i * 64 + nth_set_bit64(~w[i], r);
        r -= c;
    }
    return 0; // unreachable
}
// r-th set position over 576-bit mask
__device__ int nth_set_576(const unsigned long long* w, int r) {
    #pragma unroll
    for (int i = 0; i < 9; ++i) {
        int c = __popcll(w[i]);
        if (r < c) return i * 64 + nth_set_bit64(w[i], r);
        r -= c;
    }
    return 0; // unreachable
}

// K0: Sd head-group partials + per-wave cos scores — proven R12/R14
__global__ __launch_bounds__(256) void k_pre(
    const float* __restrict__ attn, const float* __restrict__ metric,
    const float* __restrict__ text, float* __restrict__ Sd_part,
    float* __restrict__ cos_arr)
{
    const int bid = blockIdx.x, tid = threadIdx.x;
    if (bid < 288) {
        int i = bid * 256 + tid;                  // [0, 4*BL)
        int q4 = i / BL, r = i - q4 * BL;
        int b = r / LP, j = r - b * LP;
        size_t base = ((size_t)b * H_ + 4 * q4) * L_ * L_ + 1 + j;
        const size_t LL = (size_t)L_ * L_;
        float s = (attn[base] + attn[base + LL]) +
                  (attn[base + 2 * LL] + attn[base + 3 * LL]);
        Sd_part[i] = s;
    } else {
        int wid = (bid - 288) * 4 + (tid >> 6);   // [0, BL)
        int lane = tid & 63;
        int b = wid / LP, j = wid - b * LP;
        float m = metric[((size_t)(b * L_ + 1 + j)) * CK + lane];
        float t = text[b * CK + lane];
        float d = m * t, ss = m * m, ts = t * t;
        for (int o = 32; o; o >>= 1) {
            d += __shfl_xor(d, o); ss += __shfl_xor(ss, o); ts += __shfl_xor(ts, o);
        }
        if (lane == 0)
            cos_arr[wid] = d / (sqrtf(ss) + 1e-12f) / (sqrtf(ts) + 1e-12f);
    }
}

// K1: per-(batch, slice) z-score + rank -> selbits — proven R12/R14
__global__ __launch_bounds__(256) void k_rank(
    const float* __restrict__ Sd_part, const float* __restrict__ cos_arr,
    unsigned long long* __restrict__ selbits)
{
    const int b = blockIdx.x / 9, slice = blockIdx.x % 9;
    const int tid = threadIdx.x, wv = tid >> 6, lane = tid & 63;

    __shared__ float sdv[LP];
    __shared__ float csv[LP];
    __shared__ float red[8];
    __shared__ int   prank[256];

    float sumS = 0.f, sumC = 0.f;
    for (int j = tid; j < LP; j += 256) {
        const int idx = b * LP + j;
        float Sd = (Sd_part[idx] + Sd_part[BL + idx]) +
                   (Sd_part[2 * BL + idx] + Sd_part[3 * BL + idx]);
        float cs = cos_arr[idx];
        sdv[j] = Sd; csv[j] = cs;
        sumS += Sd; sumC += cs;
    }
    {
        float a = sumS, c2 = sumC;
        for (int o = 32; o; o >>= 1) { a += __shfl_xor(a, o); c2 += __shfl_xor(c2, o); }
        if (lane == 0) { red[wv] = a; red[4 + wv] = c2; }
    }
    __syncthreads();
    const float mS = ((red[0] + red[1]) + (red[2] + red[3])) * (1.f / LP);
    const float mC = ((red[4] + red[5]) + (red[6] + red[7])) * (1.f / LP);
    __syncthreads();

    float s2S = 0.f, s2C = 0.f;
    for (int j = tid; j < LP; j += 256) {
        float dS = sdv[j] - mS, dC = csv[j] - mC;
        s2S += dS * dS; s2C += dC * dC;
    }
    {
        float a = s2S, c2 = s2C;
        for (int o = 32; o; o >>= 1) { a += __shfl_xor(a, o); c2 += __shfl_xor(c2, o); }
        if (lane == 0) { red[wv] = a; red[4 + wv] = c2; }
    }
    __syncthreads();
    const float vS = ((red[0] + red[1]) + (red[2] + red[3])) * (1.f / (LP - 1));
    const float vC = ((red[4] + red[5]) + (red[6] + red[7])) * (1.f / (LP - 1));
    const float izS = 0.5f / (sqrtf(vS) + 1e-6f);
    const float izC = 0.5f / (sqrtf(vC) + 1e-6f);
    __syncthreads();

    for (int j = tid; j < LP; j += 256)
        sdv[j] = (sdv[j] - mS) * izS + (csv[j] - mC) * izC;
    __syncthreads();

    {
        const int j = slice * 64 + lane;
        const float my = sdv[j];
        int rk = 0;
        const int k0 = 144 * wv;
        for (int k = k0; k < k0 + 144; ++k) {
            float s = sdv[k];
            rk += (s > my) || (s == my && k < j);   // stable: score desc, idx asc
        }
        prank[tid] = rk;
    }
    __syncthreads();
    if (tid < 64) {
        int tot = (prank[tid] + prank[tid + 64]) + (prank[tid + 128] + prank[tid + 192]);
        unsigned long long bm = __ballot(tot < DOM);
        if (tid == 0) selbits[b * 9 + slice] = bm;
    }
}

// K2: assignment blocks [0,256) + dominant-copy blocks [256, 256+880).
// Copies depend only on selbits, so they overlap with assignment here
// instead of serializing inside k_out.
__global__ __launch_bounds__(512) void k_assign(
    const float* __restrict__ metric, const float* __restrict__ hidden,
    const unsigned long long* __restrict__ selbits,
    int* __restrict__ assign_tok, float* __restrict__ out)
{
    const int tid = threadIdx.x;
    if (blockIdx.x < B_ * 8) {
        // ---- assignment: 8 threads/token — proven R14 ----
        const int b = blockIdx.x >> 3, sub = blockIdx.x & 7;
        const int wv = tid >> 6, lane = tid & 63;
        __shared__ int   t10[CTX];
        __shared__ float tg[CTX * CK];
        __shared__ float tinv[CTX];

        unsigned long long w[9];
        #pragma unroll
        for (int i = 0; i < 9; ++i) w[i] = selbits[b * 9 + i];

        if (tid < CTX) t10[tid] = nth_zero_576(w, 52 * tid) + 1;
        __syncthreads();
        if (tid < CTX * CK)
            tg[tid] = metric[((size_t)(b * L_ + t10[tid >> 6])) * CK + (tid & 63)];
        {
            int i2 = tid + 512;
            if (i2 < CTX * CK)
                tg[i2] = metric[((size_t)(b * L_ + t10[i2 >> 6])) * CK + (i2 & 63)];
        }
        __syncthreads();
        if (wv < 5) {
            #pragma unroll
            for (int q = 0; q < 2; ++q) {
                int k = 2 * wv + q;
                float t = tg[k * CK + lane];
                float s2 = t * t;
                for (int o = 32; o; o >>= 1) s2 += __shfl_xor(s2, o);
                if (lane == 0) tinv[k] = 1.f / (sqrtf(s2) + 1e-12f);
            }
        }
        __syncthreads();

        const int m = sub * 64 + (tid >> 3);      // token index
        const int e = tid & 7;                     // component-eighth
        const int tok = nth_zero_576(w, remain_pos(m)) + 1;
        const float4* row = (const float4*)&metric[((size_t)(b * L_ + tok)) * CK + 8 * e];
        float4 r0 = row[0], r1 = row[1];

        // merge-row norm dropped: positive scalar, argmax-invariant
        float best = -1e30f; int bk = 0;
        #pragma unroll
        for (int k = 0; k < CTX; ++k) {
            const float4* tp = (const float4*)&tg[k * CK + 8 * e];
            float4 t0 = tp[0], t1 = tp[1];
            float d = (r0.x*t0.x + r0.y*t0.y + r0.z*t0.z + r0.w*t0.w) +
                      (r1.x*t1.x + r1.y*t1.y + r1.z*t1.z + r1.w*t1.w);
            d += __shfl_xor(d, 1); d += __shfl_xor(d, 2); d += __shfl_xor(d, 4);
            d *= tinv[k];
            if (d > best) { best = d; bk = k; }   // strict >: first max (jnp.argmax)
        }
        if (e == 0) assign_tok[b * NMERGE + m] = (tok << 4) | bk;
    } else {
        // ---- dominant copies: 2 rows per block (512 thr = 2 x 256) ----
        const int i2 = (blockIdx.x - B_ * 8) * 2 + (tid >> 8);  // row idx [0,1760)
        const int t256 = tid & 255;
        const int b = i2 / NSEL, r = i2 % NSEL;
        int tok = 0;
        if (r > 0) {
            unsigned long long wsel[9];
            #pragma unroll
            for (int ii = 0; ii < 9; ++ii) wsel[ii] = selbits[b * 9 + ii];
            tok = nth_set_576(wsel, r - 1) + 1;
        }
        const float4* src = (const float4*)&hidden[((size_t)(b * L_ + tok)) * D_];
        ((float4*)&out[((size_t)(b * 65 + r)) * D_])[t256] = src[t256];
    }
}

// K3: heavy (contextual) blocks only — proven R12/R14 body
__global__ __launch_bounds__(256) void k_out(
    const float* __restrict__ hidden,
    const unsigned long long* __restrict__ selbits,
    const int* __restrict__ assign_tok, float* __restrict__ out)
{
    const int blk = blockIdx.x;          // [0, B_*CTX)
    const int tid = threadIdx.x;
    const int b = blk / CTX, k = blk % CTX;
    const int w = tid >> 6, lane = tid & 63;
    __shared__ int at[NMERGE];
    __shared__ int toks[NMERGE];
    __shared__ unsigned long long cmask[2][4];

    at[tid]       = assign_tok[b * NMERGE + tid];
    at[tid + 256] = assign_tok[b * NMERGE + tid + 256];
    __syncthreads();
    int a0 = at[tid], a1 = at[tid + 256];
    bool m0 = (a0 & 15) == k, m1 = (a1 & 15) == k;
    unsigned long long bl0 = __ballot(m0), bl1 = __ballot(m1);
    if (lane == 0) { cmask[0][w] = bl0; cmask[1][w] = bl1; }
    __syncthreads();
    int sum0 = 0, pre0 = 0, pre1 = 0;
    #pragma unroll
    for (int ww = 0; ww < 4; ++ww) {
        int p0 = __popcll(cmask[0][ww]);
        sum0 += p0;
        if (ww < w) { pre0 += p0; pre1 += __popcll(cmask[1][ww]); }
    }
    int sum1 = 0;
    #pragma unroll
    for (int ww = 0; ww < 4; ++ww) sum1 += __popcll(cmask[1][ww]);
    unsigned long long lt = (1ull << lane) - 1ull;
    if (m0) toks[pre0 + __popcll(bl0 & lt)] = a0 >> 4;
    if (m1) toks[sum0 + pre1 + __popcll(bl1 & lt)] = a1 >> 4;
    const int cnt = sum0 + sum1;
    __syncthreads();

    const float4* hb = (const float4*)&hidden[((size_t)b * L_) * D_];
    float4 a_0 = make_float4(0,0,0,0), a_1 = a_0, a_2 = a_0, a_3 = a_0;
    float4 a_4 = a_0, a_5 = a_0, a_6 = a_0, a_7 = a_0;
    int i = 0;
    for (; i + 8 <= cnt; i += 8) {
        float4 v0 = hb[(size_t)toks[i+0] * 256 + tid];
        float4 v1 = hb[(size_t)toks[i+1] * 256 + tid];
        float4 v2 = hb[(size_t)toks[i+2] * 256 + tid];
        float4 v3 = hb[(size_t)toks[i+3] * 256 + tid];
        float4 v4 = hb[(size_t)toks[i+4] * 256 + tid];
        float4 v5 = hb[(size_t)toks[i+5] * 256 + tid];
        float4 v6 = hb[(size_t)toks[i+6] * 256 + tid];
        float4 v7 = hb[(size_t)toks[i+7] * 256 + tid];
        a_0.x += v0.x; a_0.y += v0.y; a_0.z += v0.z; a_0.w += v0.w;
        a_1.x += v1.x; a_1.y += v1.y; a_1.z += v1.z; a_1.w += v1.w;
        a_2.x += v2.x; a_2.y += v2.y; a_2.z += v2.z; a_2.w += v2.w;
        a_3.x += v3.x; a_3.y += v3.y; a_3.z += v3.z; a_3.w += v3.w;
        a_4.x += v4.x; a_4.y += v4.y; a_4.z += v4.z; a_4.w += v4.w;
        a_5.x += v5.x; a_5.y += v5.y; a_5.z += v5.z; a_5.w += v5.w;
        a_6.x += v6.x; a_6.y += v6.y; a_6.z += v6.z; a_6.w += v6.w;
        a_7.x += v7.x; a_7.y += v7.y; a_7.z += v7.z; a_7.w += v7.w;
    }
    for (; i < cnt; ++i) {
        float4 v = hb[(size_t)toks[i] * 256 + tid];
        a_0.x += v.x; a_0.y += v.y; a_0.z += v.z; a_0.w += v.w;
    }
    float4 acc;
    acc.x = ((a_0.x + a_1.x) + (a_2.x + a_3.x)) + ((a_4.x + a_5.x) + (a_6.x + a_7.x));
    acc.y = ((a_0.y + a_1.y) + (a_2.y + a_3.y)) + ((a_4.y + a_5.y) + (a_6.y + a_7.y));
    acc.z = ((a_0.z + a_1.z) + (a_2.z + a_3.z)) + ((a_4.z + a_5.z) + (a_6.z + a_7.z));
    acc.w = ((a_0.w + a_1.w) + (a_2.w + a_3.w)) + ((a_4.w + a_5.w) + (a_6.w + a_7.w));

    unsigned long long wsel[9];
    #pragma unroll
    for (int ii = 0; ii < 9; ++ii) wsel[ii] = selbits[b * 9 + ii];
    const int tgt_tok = nth_zero_576(wsel, 52 * k) + 1;
    float4 bv = hb[(size_t)tgt_tok * 256 + tid];
    float inv = 1.0f / fmaxf((float)cnt, 1.0f);
    float4 o;
    o.x = bv.x + acc.x * inv; o.y = bv.y + acc.y * inv;
    o.z = bv.z + acc.z * inv; o.w = bv.w + acc.w * inv;
    ((float4*)&out[((size_t)(b * 65 + NSEL + k)) * D_])[tid] = o;
}

extern "C" void kernel_launch(void* const* d_in, const int* in_sizes, int n_in,
                              void* d_out, int out_size, void* d_ws, size_t ws_size,
                              hipStream_t stream) {
    const float* attn   = (const float*)d_in[0];
    const float* hidden = (const float*)d_in[1];
    const float* metric = (const float*)d_in[2];
    const float* text   = (const float*)d_in[3];
    float* out = (float*)d_out;

    char* ws = (char*)d_ws;
    size_t off = 0;
    auto alloc = [&](size_t bytes) { void* p = ws + off; off = (off + bytes + 255) & ~(size_t)255; return p; };
    float* Sd_part = (float*)alloc((size_t)4 * BL * 4);
    float* cos_arr = (float*)alloc((size_t)BL * 4);
    unsigned long long* selbits = (unsigned long long*)alloc((size_t)B_ * 9 * 8);
    int*   assign_tok = (int*)alloc((size_t)B_ * NMERGE * 4);

    k_pre   <<<288 + BL / 4, 256, 0, stream>>>(attn, metric, text, Sd_part, cos_arr);
    k_rank  <<<B_ * 9, 256, 0, stream>>>(Sd_part, cos_arr, selbits);
    k_assign<<<B_ * 8 + (B_ * NSEL) / 2, 512, 0, stream>>>(metric, hidden, selbits,
                                                           assign_tok, out);
    k_out   <<<B_ * CTX, 256, 0, stream>>>(hidden, selbits, assign_tok, out);
}

// Round 17
// 38.952 us; speedup vs baseline: 2.1742x; 1.0388x over previous
//
#include <hip/hip_runtime.h>

#define B_   32
#define H_   16
#define L_   577
#define D_   1024
#define CK   64
#define LP   576    // L-1 patches = 9*64 exactly
#define DOM  54
#define NSEL 55     // DOM + CLS
#define NR   522    // LP - DOM
#define CTX  10
#define NMERGE 512  // NR - CTX
#define BL   (B_ * LP)

// remain-list position for merge index m: p = m + min(m/51,9) + 1
__device__ __forceinline__ int remain_pos(int m) {
    int k = m / 51; if (k > 9) k = 9;
    return m + k + 1;
}

// position of r-th (0-indexed) set bit of x (must exist)
__device__ __forceinline__ int nth_set_bit64(unsigned long long x, int r) {
    int pos = 0;
    #pragma unroll
    for (int sh = 32; sh >= 1; sh >>= 1) {
        int c = __popcll(x & ((1ull << sh) - 1));
        if (r >= c) { r -= c; x >>= sh; pos += sh; }
    }
    return pos;
}
// r-th zero position over 576-bit mask (9 u64 words)
__device__ int nth_zero_576(const unsigned long long* w, int r) {
    #pragma unroll
    for (int i = 0; i < 9; ++i) {
        int c = 64 - __popcll(w[i]);
        if (r < c) return i * 64 + nth_set_bit64(~w[i], r);
        r -= c;
    }
    return 0; // unreachable
}
// r-th set position over 576-bit mask
__device__ int nth_set_576(const unsigned long long* w, int r) {
    #pragma unroll
    for (int i = 0; i < 9; ++i) {
        int c = __popcll(w[i]);
        if (r < c) return i * 64 + nth_set_bit64(w[i], r);
        r -= c;
    }
    return 0; // unreachable
}

// K0 (COMPACT): 72 Sd blocks (float4 over j) + 1152 cos blocks
// (16-lane groups, float4/lane, 4 rows/wave, one batch per block).
__global__ __launch_bounds__(256) void k_pre(
    const float* __restrict__ attn, const float* __restrict__ metric,
    const float* __restrict__ text, float* __restrict__ Sd_part,
    float* __restrict__ cos_arr)
{
    const int bid = blockIdx.x, tid = threadIdx.x;
    if (bid < 72) {
        // Sd partials: i = (q4, b, j4); thread sums 4 heads over 4 js (float4)
        int i = bid * 256 + tid;                  // [0, BL) = [0, 4*4608)
        int q4 = i / 4608, r = i - q4 * 4608;     // 4608 = B_ * 144
        int b = r / 144, j4 = r - b * 144;
        const size_t LL = (size_t)L_ * L_;
        size_t base = ((size_t)b * H_ + 4 * q4) * LL + 1 + 4 * j4;
        float4 s0 = *(const float4*)&attn[base];
        float4 s1 = *(const float4*)&attn[base + LL];
        float4 s2 = *(const float4*)&attn[base + 2 * LL];
        float4 s3 = *(const float4*)&attn[base + 3 * LL];
        float4 s;
        s.x = (s0.x + s1.x) + (s2.x + s3.x);
        s.y = (s0.y + s1.y) + (s2.y + s3.y);
        s.z = (s0.z + s1.z) + (s2.z + s3.z);
        s.w = (s0.w + s1.w) + (s2.w + s3.w);
        *(float4*)&Sd_part[q4 * BL + b * LP + 4 * j4] = s;
    } else {
        // cos: block serves one batch, 16 rows (4 waves x 4 rows)
        const int cb = bid - 72;                  // [0, 1152)
        const int b = cb / 36, row0 = (cb % 36) * 16;
        const int wv = tid >> 6, lane = tid & 63;
        const int g = lane >> 4, q = lane & 15;
        __shared__ float tsh[CK];
        __shared__ float invtn_sh;

        if (tid < CK) {
            float t = text[b * CK + tid];
            tsh[tid] = t;
            float s2 = t * t;
            for (int o = 32; o; o >>= 1) s2 += __shfl_xor(s2, o);
            if (tid == 0) invtn_sh = 1.f / (sqrtf(s2) + 1e-12f);
        }
        __syncthreads();

        const int j = row0 + wv * 4 + g;          // [0, 576)
        float4 mv = *(const float4*)&metric[((size_t)(b * L_ + 1 + j)) * CK + 4 * q];
        float4 tv = *(const float4*)&tsh[4 * q];
        float d  = mv.x * tv.x + mv.y * tv.y + mv.z * tv.z + mv.w * tv.w;
        float ss = mv.x * mv.x + mv.y * mv.y + mv.z * mv.z + mv.w * mv.w;
        #pragma unroll
        for (int o = 1; o < 16; o <<= 1) {        // stays within 16-lane group
            d += __shfl_xor(d, o); ss += __shfl_xor(ss, o);
        }
        if (q == 0)
            cos_arr[b * LP + j] = d / (sqrtf(ss) + 1e-12f) * invtn_sh;
    }
}

// K1: per-(batch, slice) z-score + rank -> selbits — proven R12/R14/R16
__global__ __launch_bounds__(256) void k_rank(
    const float* __restrict__ Sd_part, const float* __restrict__ cos_arr,
    unsigned long long* __restrict__ selbits)
{
    const int b = blockIdx.x / 9, slice = blockIdx.x % 9;
    const int tid = threadIdx.x, wv = tid >> 6, lane = tid & 63;

    __shared__ float sdv[LP];
    __shared__ float csv[LP];
    __shared__ float red[8];
    __shared__ int   prank[256];

    float sumS = 0.f, sumC = 0.f;
    for (int j = tid; j < LP; j += 256) {
        const int idx = b * LP + j;
        float Sd = (Sd_part[idx] + Sd_part[BL + idx]) +
                   (Sd_part[2 * BL + idx] + Sd_part[3 * BL + idx]);
        float cs = cos_arr[idx];
        sdv[j] = Sd; csv[j] = cs;
        sumS += Sd; sumC += cs;
    }
    {
        float a = sumS, c2 = sumC;
        for (int o = 32; o; o >>= 1) { a += __shfl_xor(a, o); c2 += __shfl_xor(c2, o); }
        if (lane == 0) { red[wv] = a; red[4 + wv] = c2; }
    }
    __syncthreads();
    const float mS = ((red[0] + red[1]) + (red[2] + red[3])) * (1.f / LP);
    const float mC = ((red[4] + red[5]) + (red[6] + red[7])) * (1.f / LP);
    __syncthreads();

    float s2S = 0.f, s2C = 0.f;
    for (int j = tid; j < LP; j += 256) {
        float dS = sdv[j] - mS, dC = csv[j] - mC;
        s2S += dS * dS; s2C += dC * dC;
    }
    {
        float a = s2S, c2 = s2C;
        for (int o = 32; o; o >>= 1) { a += __shfl_xor(a, o); c2 += __shfl_xor(c2, o); }
        if (lane == 0) { red[wv] = a; red[4 + wv] = c2; }
    }
    __syncthreads();
    const float vS = ((red[0] + red[1]) + (red[2] + red[3])) * (1.f / (LP - 1));
    const float vC = ((red[4] + red[5]) + (red[6] + red[7])) * (1.f / (LP - 1));
    const float izS = 0.5f / (sqrtf(vS) + 1e-6f);
    const float izC = 0.5f / (sqrtf(vC) + 1e-6f);
    __syncthreads();

    for (int j = tid; j < LP; j += 256)
        sdv[j] = (sdv[j] - mS) * izS + (csv[j] - mC) * izC;
    __syncthreads();

    {
        const int j = slice * 64 + lane;
        const float my = sdv[j];
        int rk = 0;
        const int k0 = 144 * wv;
        for (int k = k0; k < k0 + 144; ++k) {
            float s = sdv[k];
            rk += (s > my) || (s == my && k < j);   // stable: score desc, idx asc
        }
        prank[tid] = rk;
    }
    __syncthreads();
    if (tid < 64) {
        int tot = (prank[tid] + prank[tid + 64]) + (prank[tid + 128] + prank[tid + 192]);
        unsigned long long bm = __ballot(tot < DOM);
        if (tid == 0) selbits[b * 9 + slice] = bm;
    }
}

// K2: assignment blocks [0,256) + dominant-copy blocks — proven R16
__global__ __launch_bounds__(512) void k_assign(
    const float* __restrict__ metric, const float* __restrict__ hidden,
    const unsigned long long* __restrict__ selbits,
    int* __restrict__ assign_tok, float* __restrict__ out)
{
    const int tid = threadIdx.x;
    if (blockIdx.x < B_ * 8) {
        const int b = blockIdx.x >> 3, sub = blockIdx.x & 7;
        const int wv = tid >> 6, lane = tid & 63;
        __shared__ int   t10[CTX];
        __shared__ float tg[CTX * CK];
        __shared__ float tinv[CTX];

        unsigned long long w[9];
        #pragma unroll
        for (int i = 0; i < 9; ++i) w[i] = selbits[b * 9 + i];

        if (tid < CTX) t10[tid] = nth_zero_576(w, 52 * tid) + 1;
        __syncthreads();
        if (tid < CTX * CK)
            tg[tid] = metric[((size_t)(b * L_ + t10[tid >> 6])) * CK + (tid & 63)];
        {
            int i2 = tid + 512;
            if (i2 < CTX * CK)
                tg[i2] = metric[((size_t)(b * L_ + t10[i2 >> 6])) * CK + (i2 & 63)];
        }
        __syncthreads();
        if (wv < 5) {
            #pragma unroll
            for (int q = 0; q < 2; ++q) {
                int k = 2 * wv + q;
                float t = tg[k * CK + lane];
                float s2 = t * t;
                for (int o = 32; o; o >>= 1) s2 += __shfl_xor(s2, o);
                if (lane == 0) tinv[k] = 1.f / (sqrtf(s2) + 1e-12f);
            }
        }
        __syncthreads();

        const int m = sub * 64 + (tid >> 3);      // token index
        const int e = tid & 7;                     // component-eighth
        const int tok = nth_zero_576(w, remain_pos(m)) + 1;
        const float4* row = (const float4*)&metric[((size_t)(b * L_ + tok)) * CK + 8 * e];
        float4 r0 = row[0], r1 = row[1];

        // merge-row norm dropped: positive scalar, argmax-invariant
        float best = -1e30f; int bk = 0;
        #pragma unroll
        for (int k = 0; k < CTX; ++k) {
            const float4* tp = (const float4*)&tg[k * CK + 8 * e];
            float4 t0 = tp[0], t1 = tp[1];
            float d = (r0.x*t0.x + r0.y*t0.y + r0.z*t0.z + r0.w*t0.w) +
                      (r1.x*t1.x + r1.y*t1.y + r1.z*t1.z + r1.w*t1.w);
            d += __shfl_xor(d, 1); d += __shfl_xor(d, 2); d += __shfl_xor(d, 4);
            d *= tinv[k];
            if (d > best) { best = d; bk = k; }   // strict >: first max (jnp.argmax)
        }
        if (e == 0) assign_tok[b * NMERGE + m] = (tok << 4) | bk;
    } else {
        const int i2 = (blockIdx.x - B_ * 8) * 2 + (tid >> 8);  // row idx [0,1760)
        const int t256 = tid & 255;
        const int b = i2 / NSEL, r = i2 % NSEL;
        int tok = 0;
        if (r > 0) {
            unsigned long long wsel[9];
            #pragma unroll
            for (int ii = 0; ii < 9; ++ii) wsel[ii] = selbits[b * 9 + ii];
            tok = nth_set_576(wsel, r - 1) + 1;
        }
        const float4* src = (const float4*)&hidden[((size_t)(b * L_ + tok)) * D_];
        ((float4*)&out[((size_t)(b * 65 + r)) * D_])[t256] = src[t256];
    }
}

// K3: heavy (contextual) blocks only — proven R12/R14/R16 body
__global__ __launch_bounds__(256) void k_out(
    const float* __restrict__ hidden,
    const unsigned long long* __restrict__ selbits,
    const int* __restrict__ assign_tok, float* __restrict__ out)
{
    const int blk = blockIdx.x;          // [0, B_*CTX)
    const int tid = threadIdx.x;
    const int b = blk / CTX, k = blk % CTX;
    const int w = tid >> 6, lane = tid & 63;
    __shared__ int at[NMERGE];
    __shared__ int toks[NMERGE];
    __shared__ unsigned long long cmask[2][4];

    at[tid]       = assign_tok[b * NMERGE + tid];
    at[tid + 256] = assign_tok[b * NMERGE + tid + 256];
    __syncthreads();
    int a0 = at[tid], a1 = at[tid + 256];
    bool m0 = (a0 & 15) == k, m1 = (a1 & 15) == k;
    unsigned long long bl0 = __ballot(m0), bl1 = __ballot(m1);
    if (lane == 0) { cmask[0][w] = bl0; cmask[1][w] = bl1; }
    __syncthreads();
    int sum0 = 0, pre0 = 0, pre1 = 0;
    #pragma unroll
    for (int ww = 0; ww < 4; ++ww) {
        int p0 = __popcll(cmask[0][ww]);
        sum0 += p0;
        if (ww < w) { pre0 += p0; pre1 += __popcll(cmask[1][ww]); }
    }
    int sum1 = 0;
    #pragma unroll
    for (int ww = 0; ww < 4; ++ww) sum1 += __popcll(cmask[1][ww]);
    unsigned long long lt = (1ull << lane) - 1ull;
    if (m0) toks[pre0 + __popcll(bl0 & lt)] = a0 >> 4;
    if (m1) toks[sum0 + pre1 + __popcll(bl1 & lt)] = a1 >> 4;
    const int cnt = sum0 + sum1;
    __syncthreads();

    const float4* hb = (const float4*)&hidden[((size_t)b * L_) * D_];
    float4 a_0 = make_float4(0,0,0,0), a_1 = a_0, a_2 = a_0, a_3 = a_0;
    float4 a_4 = a_0, a_5 = a_0, a_6 = a_0, a_7 = a_0;
    int i = 0;
    for (; i + 8 <= cnt; i += 8) {
        float4 v0 = hb[(size_t)toks[i+0] * 256 + tid];
        float4 v1 = hb[(size_t)toks[i+1] * 256 + tid];
        float4 v2 = hb[(size_t)toks[i+2] * 256 + tid];
        float4 v3 = hb[(size_t)toks[i+3] * 256 + tid];
        float4 v4 = hb[(size_t)toks[i+4] * 256 + tid];
        float4 v5 = hb[(size_t)toks[i+5] * 256 + tid];
        float4 v6 = hb[(size_t)toks[i+6] * 256 + tid];
        float4 v7 = hb[(size_t)toks[i+7] * 256 + tid];
        a_0.x += v0.x; a_0.y += v0.y; a_0.z += v0.z; a_0.w += v0.w;
        a_1.x += v1.x; a_1.y += v1.y; a_1.z += v1.z; a_1.w += v1.w;
        a_2.x += v2.x; a_2.y += v2.y; a_2.z += v2.z; a_2.w += v2.w;
        a_3.x += v3.x; a_3.y += v3.y; a_3.z += v3.z; a_3.w += v3.w;
        a_4.x += v4.x; a_4.y += v4.y; a_4.z += v4.z; a_4.w += v4.w;
        a_5.x += v5.x; a_5.y += v5.y; a_5.z += v5.z; a_5.w += v5.w;
        a_6.x += v6.x; a_6.y += v6.y; a_6.z += v6.z; a_6.w += v6.w;
        a_7.x += v7.x; a_7.y += v7.y; a_7.z += v7.z; a_7.w += v7.w;
    }
    for (; i < cnt; ++i) {
        float4 v = hb[(size_t)toks[i] * 256 + tid];
        a_0.x += v.x; a_0.y += v.y; a_0.z += v.z; a_0.w += v.w;
    }
    float4 acc;
    acc.x = ((a_0.x + a_1.x) + (a_2.x + a_3.x)) + ((a_4.x + a_5.x) + (a_6.x + a_7.x));
    acc.y = ((a_0.y + a_1.y) + (a_2.y + a_3.y)) + ((a_4.y + a_5.y) + (a_6.y + a_7.y));
    acc.z = ((a_0.z + a_1.z) + (a_2.z + a_3.z)) + ((a_4.z + a_5.z) + (a_6.z + a_7.z));
    acc.w = ((a_0.w + a_1.w) + (a_2.w + a_3.w)) + ((a_4.w + a_5.w) + (a_6.w + a_7.w));

    unsigned long long wsel[9];
    #pragma unroll
    for (int ii = 0; ii < 9; ++ii) wsel[ii] = selbits[b * 9 + ii];
    const int tgt_tok = nth_zero_576(wsel, 52 * k) + 1;
    float4 bv = hb[(size_t)tgt_tok * 256 + tid];
    float inv = 1.0f / fmaxf((float)cnt, 1.0f);
    float4 o;
    o.x = bv.x + acc.x * inv; o.y = bv.y + acc.y * inv;
    o.z = bv.z + acc.z * inv; o.w = bv.w + acc.w * inv;
    ((float4*)&out[((size_t)(b * 65 + NSEL + k)) * D_])[tid] = o;
}

extern "C" void kernel_launch(void* const* d_in, const int* in_sizes, int n_in,
                              void* d_out, int out_size, void* d_ws, size_t ws_size,
                              hipStream_t stream) {
    const float* attn   = (const float*)d_in[0];
    const float* hidden = (const float*)d_in[1];
    const float* metric = (const float*)d_in[2];
    const float* text   = (const float*)d_in[3];
    float* out = (float*)d_out;

    char* ws = (char*)d_ws;
    size_t off = 0;
    auto alloc = [&](size_t bytes) { void* p = ws + off; off = (off + bytes + 255) & ~(size_t)255; return p; };
    float* Sd_part = (float*)alloc((size_t)4 * BL * 4);
    float* cos_arr = (float*)alloc((size_t)BL * 4);
    unsigned long long* selbits = (unsigned long long*)alloc((size_t)B_ * 9 * 8);
    int*   assign_tok = (int*)alloc((size_t)B_ * NMERGE * 4);

    k_pre   <<<72 + 1152, 256, 0, stream>>>(attn, metric, text, Sd_part, cos_arr);
    k_rank  <<<B_ * 9, 256, 0, stream>>>(Sd_part, cos_arr, selbits);
    k_assign<<<B_ * 8 + (B_ * NSEL) / 2, 512, 0, stream>>>(metric, hidden, selbits,
                                                           assign_tok, out);
    k_out   <<<B_ * CTX, 256, 0, stream>>>(hidden, selbits, assign_tok, out);
}